// Round 9
// baseline (137.253 us; speedup 1.0000x reference)
//
#include <hip/hip_runtime.h>
#include <cstdint>
#include <cstddef>

// Problem: B=8, C=64, H=W=32 -> N=8192 nodes, K=9 neighbors, OUT=64.
// Batches: b = [1024b,1024(b+1)) for b<=6, batch 7 = [7168,8190], batch 8 = {8191}.
// Node g <-> (b = g>>10, hw = g&1023); features x[b][c][hw] (node 8191 -> b=7).
//
// R15 == R14 resubmit (round 8 was an infra failure: container died, kernel
//  never ran; re-audit found no defects).
// R14: R13 revealed the truth: total = fill(46, fixed) + kernel + ~3 gap; the
//  kernel (55.5us, VALUBusy 34%, 8 waves/CU) is latency-bound, not
//  throughput-bound. Occupancy is pinned by rows-per-wave (8192/rows = waves).
//  -> 2 rows/wave: 4096 waves = 16/CU (4/SIMD). 1024 blocks x 8 rows.
//  Wave owns rows {n0+2w, +1}; lane owns 16 cols as 4 f4-groups at 256-col
//  stride (jj = 256q+4*lane+e = R12 key layout) -> dist lives in acc REGISTERS
//  and cand builds directly from them: no dist-LDS round trip, fewer barriers,
//  proven tournament verbatim. K-slices of 8 ch (32KB) -> LDS 38.9KB -> 4
//  blocks/CU at launch_bounds(256,4) (acc only 32 VGPR).
//  Exactness preserved: ascending-ch fmaf chains for dot and sq on identical
//  staged bits; d = (si+sj) - 2*acc -> d(n,n) == 0 exactly; unique keys ->
//  lax.top_k smaller-index tie-break.

__global__ __launch_bounds__(256, 4) void k_all(const float* __restrict__ x,
                                                const float* __restrict__ Wl,
                                                const float* __restrict__ bl,
                                                const float* __restrict__ Wr,
                                                float* __restrict__ out) {
  // SH = Xs[8][1024] (32KB) | Asf[64][8] (2KB) | sqX[1024] (4KB) = 38912 B.
  // Ws overlay after select: WsL @0 (64x65), WsR @4160 (64x65) -> 8320 floats
  // over dead Xs+Asf; sqX region untouched (also dead).
  __shared__ float SH[9728];
  float* Xs = SH;
  float* Asf = SH + 8192;
  float* sqX = SH + 8704;
  float4* Xs4 = (float4*)Xs;
  float4* sqX4 = (float4*)sqX;

  int bi = (int)blockIdx.x, t = threadIdx.x;
  int lane = t & 63, w = t >> 6;
  int n0 = bi << 3;                  // 8 rows/block; batch bounds are 8-aligned
  int s = (n0 >= 7168) ? 7168 : (n0 & ~1023);
  const float* xb = x + (((size_t)(s >> 10)) << 16);     // batch base
  const float* xrow = x + (((size_t)(n0 >> 10)) << 16) + (n0 & 1023);

  // stage A: 8 rows x 64 ch -> Asf[ch][row]; 128 threads, one f4 (4 rows) each
  if (t < 128) {
    int ch = t >> 1, hf = t & 1;
    *(float4*)&Asf[(ch << 3) + (hf << 2)] =
        *(const float4*)&xrow[((size_t)ch << 10) + (hf << 2)];
  }

  float acc[2][16];
#pragma unroll
  for (int r = 0; r < 2; ++r)
#pragma unroll
    for (int c = 0; c < 16; ++c) acc[r][c] = 0.f;
  float4 p4 = {0.f, 0.f, 0.f, 0.f};  // sq partial for cols 4t..4t+3

#pragma unroll 1
  for (int ks = 0; ks < 8; ++ks) {
    if (ks) __syncthreads();         // prev-slice LDS reads done before restage
    int k0 = ks << 3;
    // stage slice: 8 ch x 1024 cols, f4 copy (coalesced 1KB/instr)
#pragma unroll
    for (int i = 0; i < 8; ++i) {
      int lin = t + (i << 8);
      int kc = lin >> 8, j4 = lin & 255;
      Xs4[(kc << 8) + j4] =
          *(const float4*)&xb[((size_t)(k0 + kc) << 10) + (j4 << 2)];
    }
    __syncthreads();
    // sq partial: ascending-ch fmaf chain == dot chain -> exact self-cancel
#pragma unroll
    for (int kc = 0; kc < 8; ++kc) {
      float4 v = Xs4[(kc << 8) + t];
      p4.x = fmaf(v.x, v.x, p4.x);
      p4.y = fmaf(v.y, v.y, p4.y);
      p4.z = fmaf(v.z, v.z, p4.z);
      p4.w = fmaf(v.w, v.w, p4.w);
    }
    // GEMM: per ch, 1 broadcast b64 (A: 2 rows) + 4 lane-contig b128 (B) + 32 FMA
#pragma unroll
    for (int kc = 0; kc < 8; ++kc) {
      float2 a = *(const float2*)&Asf[((k0 + kc) << 3) + (w << 1)];
      float4 b0 = Xs4[(kc << 8) + lane];
      float4 b1 = Xs4[(kc << 8) + 64 + lane];
      float4 b2 = Xs4[(kc << 8) + 128 + lane];
      float4 b3 = Xs4[(kc << 8) + 192 + lane];
      float bv[16] = {b0.x, b0.y, b0.z, b0.w, b1.x, b1.y, b1.z, b1.w,
                      b2.x, b2.y, b2.z, b2.w, b3.x, b3.y, b3.z, b3.w};
#pragma unroll
      for (int c = 0; c < 16; ++c) {
        acc[0][c] = fmaf(a.x, bv[c], acc[0][c]);
        acc[1][c] = fmaf(a.y, bv[c], acc[1][c]);
      }
    }
  }
  sqX4[t] = p4;
  __syncthreads();                   // sqX visible; last slice reads done

  // select: wave w owns rows n0+2w, n0+2w+1. Keys from acc REGISTERS.
  float4 sq4[4];
#pragma unroll
  for (int q = 0; q < 4; ++q) sq4[q] = sqX4[(q << 6) + lane];

  float msum[2], xr[2];
  int cnt[2];
#pragma unroll 1
  for (int rr = 0; rr < 2; ++rr) {
    int n = n0 + (w << 1) + rr;
    float xself = x[(((size_t)(n >> 10)) << 16) + ((size_t)lane << 10) + (n & 1023)];
    xr[rr] = xself;
    if (n == 8191) { msum[rr] = xself; cnt[rr] = 1; continue; }  // singleton
    cnt[rr] = 9;
    float si = sqX[n - s];
    bool mlast = (n >= 7168);        // batch-7 rows exclude jj=1023 (node 8191)
    unsigned long long cand[16];
#pragma unroll
    for (int q = 0; q < 4; ++q) {
      float sj[4] = {sq4[q].x, sq4[q].y, sq4[q].z, sq4[q].w};
#pragma unroll
      for (int e = 0; e < 4; ++e) {
        float d = (si + sj[e]) - 2.f * acc[rr][(q << 2) + e];
        unsigned u = __float_as_uint(d);
        u = (u & 0x80000000u) ? ~u : (u | 0x80000000u);
        unsigned jj = (unsigned)((q << 8) + (lane << 2) + e);
        cand[(q << 2) + e] = ((unsigned long long)u << 32) | jj;
      }
    }
    if (mlast && lane == 63) cand[15] = ~0ull;   // jj=1023 -> q=3,lane=63,e=3
    // per-lane top-2 cache
    unsigned long long m1 = cand[0], m2 = cand[1];
    if (m2 < m1) { unsigned long long tt = m1; m1 = m2; m2 = tt; }
#pragma unroll
    for (int q = 2; q < 16; ++q) {
      unsigned long long c = cand[q];
      unsigned long long lo = (c < m1) ? c : m1;
      unsigned long long hi = (c < m1) ? m1 : c;
      m2 = (hi < m2) ? hi : m2;
      m1 = lo;
    }
    unsigned long long lm = m1;
    unsigned rmask = 0;
    bool stale = false;
    unsigned jloc[9];
#pragma unroll
    for (int kk = 0; kk < 9; ++kk) {
      unsigned long long g = lm;
#pragma unroll
      for (int off = 32; off; off >>= 1) {
        unsigned ghi = __shfl_xor((unsigned)(g >> 32), off, 64);
        unsigned glo = __shfl_xor((unsigned)g, off, 64);
        unsigned long long o = ((unsigned long long)ghi << 32) | glo;
        g = (o < g) ? o : g;
      }
      jloc[kk] = (unsigned)g & 1023u;
      if (lm == g) {                 // exactly one winner lane (unique keys)
        unsigned slot = (((unsigned)g >> 6) & 12u) | ((unsigned)g & 3u);
        rmask |= 1u << slot;
        if (!stale) { lm = m2; stale = true; }
        else {                       // rare: rescan excluding removed slots
          unsigned long long best = ~0ull;
#pragma unroll
          for (int q = 0; q < 16; ++q) {
            bool alive = ((rmask >> q) & 1u) == 0u;
            unsigned long long c = cand[q];
            best = (alive && c < best) ? c : best;
          }
          lm = best;
        }
      }
    }
    // 9 independent gathers (wave-uniform jj; lane = channel), tree sum
    const float* gx = xb + ((size_t)lane << 10);
    float g0 = gx[jloc[0]], g1 = gx[jloc[1]], g2 = gx[jloc[2]];
    float g3 = gx[jloc[3]], g4 = gx[jloc[4]], g5 = gx[jloc[5]];
    float g6 = gx[jloc[6]], g7 = gx[jloc[7]], g8 = gx[jloc[8]];
    msum[rr] = (((g0 + g1) + (g2 + g3)) + ((g4 + g5) + (g6 + g7))) + g8;
  }
  __syncthreads();                   // all Xs/sqX reads done before Ws overlay

  // stage Ws over dead Xs/Asf: WsL [64][65] @0, WsR @4160 (2 lanes/bank reads)
#pragma unroll
  for (int i = 0; i < 16; ++i) {
    int lin = t + (i << 8);
    int o = lin >> 6, c = lin & 63;
    SH[o * 65 + c] = Wl[lin];
    SH[4160 + o * 65 + c] = Wr[lin];
  }
  __syncthreads();

  // transform: lane = output channel; mean-then-linear (= reference order)
  float bias = bl[lane];
  float ms[2];
#pragma unroll
  for (int rr = 0; rr < 2; ++rr)
    ms[rr] = (cnt[rr] == 9) ? msum[rr] * (1.f / 9.f) : msum[rr];
  float accL[2] = {0.f, 0.f};
  float accR[2] = {0.f, 0.f};
#pragma unroll
  for (int c = 0; c < 64; ++c) {
    float wlc = SH[lane * 65 + c];
    float wrc = SH[4160 + lane * 65 + c];
#pragma unroll
    for (int rr = 0; rr < 2; ++rr) {
      float mc = __int_as_float(__builtin_amdgcn_readlane(__float_as_int(ms[rr]), c));
      float xc = __int_as_float(__builtin_amdgcn_readlane(__float_as_int(xr[rr]), c));
      accL[rr] = fmaf(mc, wlc, accL[rr]);
      accR[rr] = fmaf(xc, wrc, accR[rr]);
    }
  }
#pragma unroll
  for (int rr = 0; rr < 2; ++rr)
    __builtin_nontemporal_store(accL[rr] + accR[rr] + bias,
                                &out[((size_t)(n0 + (w << 1) + rr) << 6) + lane]);
}

// ---------------------------------------------------------------------------
extern "C" void kernel_launch(void* const* d_in, const int* in_sizes, int n_in,
                              void* d_out, int out_size, void* d_ws, size_t ws_size,
                              hipStream_t stream) {
  const float* x  = (const float*)d_in[0];   // (8,64,32,32)
  const float* Wl = (const float*)d_in[1];   // (64,64)
  const float* bl = (const float*)d_in[2];   // (64,)
  const float* Wr = (const float*)d_in[3];   // (64,64)
  float* out = (float*)d_out;                // (8192,64)
  (void)d_ws; (void)ws_size;                 // workspace unused

  k_all<<<dim3(1024), 256, 0, stream>>>(x, Wl, bl, Wr, out);
}

// Round 10
// 108.464 us; speedup vs baseline: 1.2654x; 1.2654x over previous
//
#include <hip/hip_runtime.h>
#include <cstdint>
#include <cstddef>

// Problem: B=8, C=64, H=W=32 -> N=8192 nodes, K=9 neighbors, OUT=64.
// Batches: b = [1024b,1024(b+1)) for b<=6, batch 7 = [7168,8190], batch 8 = {8191}.
// Node g <-> (b = g>>10, hw = g&1023); features x[b][c][hw] (node 8191 -> b=7).
//
// R16: R15's regression diagnosed from counters: VGPR 128->64 + WRITE_SIZE
//  2MB->223MB = acc[2][16] demoted to SCRATCH. Cause: cand built from
//  acc[rr][..] inside a '#pragma unroll 1' row loop -> runtime index rr ->
//  whole acc array in local memory -> every GEMM FMA round-trips scratch
//  (guide rule #20). FIX: '#pragma unroll 2' on the row loop (full unroll ->
//  rr constant-folded -> acc stays in VGPRs); continue -> if/else.
//  Structure unchanged from R14: 1024 blocks x 8 rows, 2 rows/wave -> 4096
//  waves = 16/CU; dist in registers (no LDS round-trip); K-slices of 8 ch;
//  LDS 38.9KB -> 4 blocks/CU at launch_bounds(256,4).
//  Exactness: ascending-ch fmaf chains for dot and sq on identical staged
//  bits; d = (si+sj) - 2*acc -> d(n,n) == 0 exactly; unique keys (dist|jj) ->
//  lax.top_k smaller-index tie-break.

__global__ __launch_bounds__(256, 4) void k_all(const float* __restrict__ x,
                                                const float* __restrict__ Wl,
                                                const float* __restrict__ bl,
                                                const float* __restrict__ Wr,
                                                float* __restrict__ out) {
  // SH = Xs[8][1024] (32KB) | Asf[64][8] (2KB) | sqX[1024] (4KB) = 38912 B.
  // Ws overlay after select: WsL @0 (64x65), WsR @4160 (64x65) -> 8320 floats
  // over dead Xs+Asf; sqX region untouched (also dead).
  __shared__ float SH[9728];
  float* Xs = SH;
  float* Asf = SH + 8192;
  float* sqX = SH + 8704;
  float4* Xs4 = (float4*)Xs;
  float4* sqX4 = (float4*)sqX;

  int bi = (int)blockIdx.x, t = threadIdx.x;
  int lane = t & 63, w = t >> 6;
  int n0 = bi << 3;                  // 8 rows/block; batch bounds are 8-aligned
  int s = (n0 >= 7168) ? 7168 : (n0 & ~1023);
  const float* xb = x + (((size_t)(s >> 10)) << 16);     // batch base
  const float* xrow = x + (((size_t)(n0 >> 10)) << 16) + (n0 & 1023);

  // stage A: 8 rows x 64 ch -> Asf[ch][row]; 128 threads, one f4 (4 rows) each
  if (t < 128) {
    int ch = t >> 1, hf = t & 1;
    *(float4*)&Asf[(ch << 3) + (hf << 2)] =
        *(const float4*)&xrow[((size_t)ch << 10) + (hf << 2)];
  }

  float acc[2][16];
#pragma unroll
  for (int r = 0; r < 2; ++r)
#pragma unroll
    for (int c = 0; c < 16; ++c) acc[r][c] = 0.f;
  float4 p4 = {0.f, 0.f, 0.f, 0.f};  // sq partial for cols 4t..4t+3

#pragma unroll 1
  for (int ks = 0; ks < 8; ++ks) {
    if (ks) __syncthreads();         // prev-slice LDS reads done before restage
    int k0 = ks << 3;
    // stage slice: 8 ch x 1024 cols, f4 copy (coalesced 1KB/instr)
#pragma unroll
    for (int i = 0; i < 8; ++i) {
      int lin = t + (i << 8);
      int kc = lin >> 8, j4 = lin & 255;
      Xs4[(kc << 8) + j4] =
          *(const float4*)&xb[((size_t)(k0 + kc) << 10) + (j4 << 2)];
    }
    __syncthreads();
    // sq partial: ascending-ch fmaf chain == dot chain -> exact self-cancel
#pragma unroll
    for (int kc = 0; kc < 8; ++kc) {
      float4 v = Xs4[(kc << 8) + t];
      p4.x = fmaf(v.x, v.x, p4.x);
      p4.y = fmaf(v.y, v.y, p4.y);
      p4.z = fmaf(v.z, v.z, p4.z);
      p4.w = fmaf(v.w, v.w, p4.w);
    }
    // GEMM: per ch, 1 broadcast b64 (A: 2 rows) + 4 lane-contig b128 (B) + 32 FMA
#pragma unroll
    for (int kc = 0; kc < 8; ++kc) {
      float2 a = *(const float2*)&Asf[((k0 + kc) << 3) + (w << 1)];
      float4 b0 = Xs4[(kc << 8) + lane];
      float4 b1 = Xs4[(kc << 8) + 64 + lane];
      float4 b2 = Xs4[(kc << 8) + 128 + lane];
      float4 b3 = Xs4[(kc << 8) + 192 + lane];
      float bv[16] = {b0.x, b0.y, b0.z, b0.w, b1.x, b1.y, b1.z, b1.w,
                      b2.x, b2.y, b2.z, b2.w, b3.x, b3.y, b3.z, b3.w};
#pragma unroll
      for (int c = 0; c < 16; ++c) {
        acc[0][c] = fmaf(a.x, bv[c], acc[0][c]);
        acc[1][c] = fmaf(a.y, bv[c], acc[1][c]);
      }
    }
  }
  sqX4[t] = p4;
  __syncthreads();                   // sqX visible; last slice reads done

  // select: wave w owns rows n0+2w, n0+2w+1. Keys from acc REGISTERS.
  float4 sq4[4];
#pragma unroll
  for (int q = 0; q < 4; ++q) sq4[q] = sqX4[(q << 6) + lane];

  float msum[2], xr[2];
  int cnt[2];
  // FULL unroll (trip 2): rr must be compile-time or acc demotes to scratch
  // (rule #20; R15's 88us regression).
#pragma unroll 2
  for (int rr = 0; rr < 2; ++rr) {
    int n = n0 + (w << 1) + rr;
    float xself = x[(((size_t)(n >> 10)) << 16) + ((size_t)lane << 10) + (n & 1023)];
    xr[rr] = xself;
    if (n == 8191) {                 // singleton batch: self only
      msum[rr] = xself;
      cnt[rr] = 1;
    } else {
      cnt[rr] = 9;
      float si = sqX[n - s];
      bool mlast = (n >= 7168);      // batch-7 rows exclude jj=1023 (node 8191)
      unsigned long long cand[16];
#pragma unroll
      for (int q = 0; q < 4; ++q) {
        float sj[4] = {sq4[q].x, sq4[q].y, sq4[q].z, sq4[q].w};
#pragma unroll
        for (int e = 0; e < 4; ++e) {
          float d = (si + sj[e]) - 2.f * acc[rr][(q << 2) + e];
          unsigned u = __float_as_uint(d);
          u = (u & 0x80000000u) ? ~u : (u | 0x80000000u);
          unsigned jj = (unsigned)((q << 8) + (lane << 2) + e);
          cand[(q << 2) + e] = ((unsigned long long)u << 32) | jj;
        }
      }
      if (mlast && lane == 63) cand[15] = ~0ull;  // jj=1023 -> q=3,lane=63,e=3
      // per-lane top-2 cache
      unsigned long long m1 = cand[0], m2 = cand[1];
      if (m2 < m1) { unsigned long long tt = m1; m1 = m2; m2 = tt; }
#pragma unroll
      for (int q = 2; q < 16; ++q) {
        unsigned long long c = cand[q];
        unsigned long long lo = (c < m1) ? c : m1;
        unsigned long long hi = (c < m1) ? m1 : c;
        m2 = (hi < m2) ? hi : m2;
        m1 = lo;
      }
      unsigned long long lm = m1;
      unsigned rmask = 0;
      bool stale = false;
      unsigned jloc[9];
#pragma unroll
      for (int kk = 0; kk < 9; ++kk) {
        unsigned long long g = lm;
#pragma unroll
        for (int off = 32; off; off >>= 1) {
          unsigned ghi = __shfl_xor((unsigned)(g >> 32), off, 64);
          unsigned glo = __shfl_xor((unsigned)g, off, 64);
          unsigned long long o = ((unsigned long long)ghi << 32) | glo;
          g = (o < g) ? o : g;
        }
        jloc[kk] = (unsigned)g & 1023u;
        if (lm == g) {               // exactly one winner lane (unique keys)
          unsigned slot = (((unsigned)g >> 6) & 12u) | ((unsigned)g & 3u);
          rmask |= 1u << slot;
          if (!stale) { lm = m2; stale = true; }
          else {                     // rare: rescan excluding removed slots
            unsigned long long best = ~0ull;
#pragma unroll
            for (int q = 0; q < 16; ++q) {
              bool alive = ((rmask >> q) & 1u) == 0u;
              unsigned long long c = cand[q];
              best = (alive && c < best) ? c : best;
            }
            lm = best;
          }
        }
      }
      // 9 independent gathers (wave-uniform jj; lane = channel), tree sum
      const float* gx = xb + ((size_t)lane << 10);
      float g0 = gx[jloc[0]], g1 = gx[jloc[1]], g2 = gx[jloc[2]];
      float g3 = gx[jloc[3]], g4 = gx[jloc[4]], g5 = gx[jloc[5]];
      float g6 = gx[jloc[6]], g7 = gx[jloc[7]], g8 = gx[jloc[8]];
      msum[rr] = (((g0 + g1) + (g2 + g3)) + ((g4 + g5) + (g6 + g7))) + g8;
    }
  }
  __syncthreads();                   // all Xs/sqX reads done before Ws overlay

  // stage Ws over dead Xs/Asf: WsL [64][65] @0, WsR @4160 (2 lanes/bank reads)
#pragma unroll
  for (int i = 0; i < 16; ++i) {
    int lin = t + (i << 8);
    int o = lin >> 6, c = lin & 63;
    SH[o * 65 + c] = Wl[lin];
    SH[4160 + o * 65 + c] = Wr[lin];
  }
  __syncthreads();

  // transform: lane = output channel; mean-then-linear (= reference order)
  float bias = bl[lane];
  float ms[2];
#pragma unroll
  for (int rr = 0; rr < 2; ++rr)
    ms[rr] = (cnt[rr] == 9) ? msum[rr] * (1.f / 9.f) : msum[rr];
  float accL[2] = {0.f, 0.f};
  float accR[2] = {0.f, 0.f};
#pragma unroll
  for (int c = 0; c < 64; ++c) {
    float wlc = SH[lane * 65 + c];
    float wrc = SH[4160 + lane * 65 + c];
#pragma unroll
    for (int rr = 0; rr < 2; ++rr) {
      float mc = __int_as_float(__builtin_amdgcn_readlane(__float_as_int(ms[rr]), c));
      float xc = __int_as_float(__builtin_amdgcn_readlane(__float_as_int(xr[rr]), c));
      accL[rr] = fmaf(mc, wlc, accL[rr]);
      accR[rr] = fmaf(xc, wrc, accR[rr]);
    }
  }
#pragma unroll
  for (int rr = 0; rr < 2; ++rr)
    __builtin_nontemporal_store(accL[rr] + accR[rr] + bias,
                                &out[((size_t)(n0 + (w << 1) + rr) << 6) + lane]);
}

// ---------------------------------------------------------------------------
extern "C" void kernel_launch(void* const* d_in, const int* in_sizes, int n_in,
                              void* d_out, int out_size, void* d_ws, size_t ws_size,
                              hipStream_t stream) {
  const float* x  = (const float*)d_in[0];   // (8,64,32,32)
  const float* Wl = (const float*)d_in[1];   // (64,64)
  const float* bl = (const float*)d_in[2];   // (64,)
  const float* Wr = (const float*)d_in[3];   // (64,64)
  float* out = (float*)d_out;                // (8192,64)
  (void)d_ws; (void)ws_size;                 // workspace unused

  k_all<<<dim3(1024), 256, 0, stream>>>(x, Wl, bl, Wr, out);
}

// Round 11
// 106.961 us; speedup vs baseline: 1.2832x; 1.0141x over previous
//
#include <hip/hip_runtime.h>
#include <cstdint>
#include <cstddef>

// Problem: B=8, C=64, H=W=32 -> N=8192 nodes, K=9 neighbors, OUT=64.
// Batches: b = [1024b,1024(b+1)) for b<=6, batch 7 = [7168,8190], batch 8 = {8191}.
// Node g <-> (b = g>>10, hw = g&1023); features x[b][c][hw] (node 8191 -> b=7).
//
// R17: DS-pipe decongestion. R13 (55.5us) vs R16 (59.4us) showed occupancy x2
//  doesn't pay when each wave hauls the full 256KB batch slab through LDS.
//  New: 512 blocks x 16 rows, 4 rows/wave (2x amortization vs R16), and the
//  B operand NEVER touches LDS: each lane loads its 16 owned cols directly
//  from global (x is 2MB = L2-resident; xb + ch*1024 + q*256 + 4*lane is a
//  coalesced 1KB/instr f4 load). Eliminates staging writes, all B ds_reads,
//  the separate sq pass, and every main-loop barrier. sq lives in lane regs
//  (same ascending-ch fmaf chain as dot -> d(n,n)==0 bit-exact); per-row si
//  via static 16-way cndmask select + readlane from the owner lane (no LDS,
//  no runtime indexing / rule #20). LDS keeps only A (16x64, broadcast b128)
//  + W overlay = 33.3KB -> 2 blocks/CU (512 blocks = exactly resident).
//  Tournament / gathers / transform: R16-proven code verbatim (same key
//  layout jj = 256q+4*lane+e, same d expression -> identical output bits).

__global__ __launch_bounds__(256, 2) void k_all(const float* __restrict__ x,
                                                const float* __restrict__ Wl,
                                                const float* __restrict__ bl,
                                                const float* __restrict__ Wr,
                                                float* __restrict__ out) {
  // SH: A as float4[64ch][4grp] (4KB, rows n0+4g..+3 per grp) until GEMM done;
  // then W overlay WsL [64][65] @0, WsR @4160 (8320 floats total).
  __shared__ float SH[8320];
  float4* Asf4 = (float4*)SH;

  int bi = (int)blockIdx.x, t = threadIdx.x;
  int lane = t & 63, w = t >> 6;
  int n0 = bi << 4;                  // 16 rows/block; batch bounds 16-aligned
  int s = (n0 >= 7168) ? 7168 : (n0 & ~1023);
  const float* xb = x + ((size_t)(s >> 10) << 16);       // batch plane base
  const float* xrow = x + ((size_t)(n0 >> 10) << 16) + (n0 & 1023);

  // stage A: ch = t>>2, grp g = t&3 -> rows n0+4g..n0+4g+3 of channel ch
  {
    int ch = t >> 2, g = t & 3;
    Asf4[t] = *(const float4*)&xrow[((size_t)ch << 10) + (g << 2)];
  }
  __syncthreads();

  // own-rows feature (ch=lane) for transform + singleton; read before overlay
  float4 av = Asf4[(lane << 2) + w];

  float acc[4][16];                  // rows 4w..4w+3 x lane's 16 cols
  float sqa[16];                     // lane's 16 col sq (ascending-ch chain)
#pragma unroll
  for (int r = 0; r < 4; ++r)
#pragma unroll
    for (int j = 0; j < 16; ++j) acc[r][j] = 0.f;
#pragma unroll
  for (int j = 0; j < 16; ++j) sqa[j] = 0.f;

  const float* xl = xb + (lane << 2);
#pragma unroll 4
  for (int ch = 0; ch < 64; ++ch) {
    float4 a4 = Asf4[(ch << 2) + w];                     // broadcast b128
    const float* xc = xl + ((size_t)ch << 10);
    float4 b0 = *(const float4*)&xc[0];                  // cols 4*lane..+3
    float4 b1 = *(const float4*)&xc[256];                // 256+4*lane..
    float4 b2 = *(const float4*)&xc[512];
    float4 b3 = *(const float4*)&xc[768];
    float bv[16] = {b0.x, b0.y, b0.z, b0.w, b1.x, b1.y, b1.z, b1.w,
                    b2.x, b2.y, b2.z, b2.w, b3.x, b3.y, b3.z, b3.w};
    float ar[4] = {a4.x, a4.y, a4.z, a4.w};
#pragma unroll
    for (int j = 0; j < 16; ++j) {
      sqa[j] = fmaf(bv[j], bv[j], sqa[j]);
      acc[0][j] = fmaf(ar[0], bv[j], acc[0][j]);
      acc[1][j] = fmaf(ar[1], bv[j], acc[1][j]);
      acc[2][j] = fmaf(ar[2], bv[j], acc[2][j]);
      acc[3][j] = fmaf(ar[3], bv[j], acc[3][j]);
    }
  }

  // select per row: keys from registers. jj = 256q + 4*lane + e (R16 layout).
  float msum[4];
  int cnt[4];
#pragma unroll 4
  for (int rr = 0; rr < 4; ++rr) {
    int n = n0 + (w << 2) + rr;
    float xself = (rr == 0) ? av.x : (rr == 1) ? av.y : (rr == 2) ? av.z : av.w;
    if (n == 8191) {                 // singleton batch: self only
      msum[rr] = xself;
      cnt[rr] = 1;
    } else {
      cnt[rr] = 9;
      int ln = n - s;                // self col, local
      // si = sqa[slot_o] on owner lane; static cndmask select (rule #20)
      int slot_o = ((ln >> 8) << 2) | (ln & 3);
      float sv = sqa[0];
#pragma unroll
      for (int j = 1; j < 16; ++j) sv = (slot_o == j) ? sqa[j] : sv;
      float si = __int_as_float(
          __builtin_amdgcn_readlane(__float_as_int(sv), (ln & 255) >> 2));
      bool mlast = (n >= 7168);      // batch-7 rows exclude jj=1023 (node 8191)
      unsigned long long cand[16];
#pragma unroll
      for (int q = 0; q < 4; ++q) {
#pragma unroll
        for (int e = 0; e < 4; ++e) {
          float d = (si + sqa[(q << 2) + e]) - 2.f * acc[rr][(q << 2) + e];
          unsigned u = __float_as_uint(d);
          u = (u & 0x80000000u) ? ~u : (u | 0x80000000u);
          unsigned jj = (unsigned)((q << 8) + (lane << 2) + e);
          cand[(q << 2) + e] = ((unsigned long long)u << 32) | jj;
        }
      }
      if (mlast && lane == 63) cand[15] = ~0ull;  // jj=1023 -> q=3,lane=63,e=3
      // per-lane top-2 cache
      unsigned long long m1 = cand[0], m2 = cand[1];
      if (m2 < m1) { unsigned long long tt = m1; m1 = m2; m2 = tt; }
#pragma unroll
      for (int q = 2; q < 16; ++q) {
        unsigned long long c = cand[q];
        unsigned long long lo = (c < m1) ? c : m1;
        unsigned long long hi = (c < m1) ? m1 : c;
        m2 = (hi < m2) ? hi : m2;
        m1 = lo;
      }
      unsigned long long lm = m1;
      unsigned rmask = 0;
      bool stale = false;
      unsigned jloc[9];
#pragma unroll
      for (int kk = 0; kk < 9; ++kk) {
        unsigned long long g = lm;
#pragma unroll
        for (int off = 32; off; off >>= 1) {
          unsigned ghi = __shfl_xor((unsigned)(g >> 32), off, 64);
          unsigned glo = __shfl_xor((unsigned)g, off, 64);
          unsigned long long o = ((unsigned long long)ghi << 32) | glo;
          g = (o < g) ? o : g;
        }
        jloc[kk] = (unsigned)g & 1023u;
        if (lm == g) {               // exactly one winner lane (unique keys)
          unsigned slot = (((unsigned)g >> 6) & 12u) | ((unsigned)g & 3u);
          rmask |= 1u << slot;
          if (!stale) { lm = m2; stale = true; }
          else {                     // rare: rescan excluding removed slots
            unsigned long long best = ~0ull;
#pragma unroll
            for (int q = 0; q < 16; ++q) {
              bool alive = ((rmask >> q) & 1u) == 0u;
              unsigned long long c = cand[q];
              best = (alive && c < best) ? c : best;
            }
            lm = best;
          }
        }
      }
      // 9 independent gathers (wave-uniform jj; lane = channel), tree sum
      const float* gx = xb + ((size_t)lane << 10);
      float g0 = gx[jloc[0]], g1 = gx[jloc[1]], g2 = gx[jloc[2]];
      float g3 = gx[jloc[3]], g4 = gx[jloc[4]], g5 = gx[jloc[5]];
      float g6 = gx[jloc[6]], g7 = gx[jloc[7]], g8 = gx[jloc[8]];
      msum[rr] = (((g0 + g1) + (g2 + g3)) + ((g4 + g5) + (g6 + g7))) + g8;
    }
  }
  __syncthreads();                   // all A reads done before W overlay

  // stage Ws over dead A: WsL [64][65] @0, WsR @4160 (2 lanes/bank on read)
#pragma unroll
  for (int i = 0; i < 16; ++i) {
    int lin = t + (i << 8);
    int o = lin >> 6, c = lin & 63;
    SH[o * 65 + c] = Wl[lin];
    SH[4160 + o * 65 + c] = Wr[lin];
  }
  __syncthreads();

  // transform: lane = output channel; mean-then-linear (= reference order)
  float bias = bl[lane];
  float ms[4];
#pragma unroll
  for (int rr = 0; rr < 4; ++rr)
    ms[rr] = (cnt[rr] == 9) ? msum[rr] * (1.f / 9.f) : msum[rr];
  float xr[4] = {av.x, av.y, av.z, av.w};
  float accL[4] = {0.f, 0.f, 0.f, 0.f};
  float accR[4] = {0.f, 0.f, 0.f, 0.f};
#pragma unroll
  for (int c = 0; c < 64; ++c) {
    float wlc = SH[lane * 65 + c];
    float wrc = SH[4160 + lane * 65 + c];
#pragma unroll
    for (int rr = 0; rr < 4; ++rr) {
      float mc = __int_as_float(__builtin_amdgcn_readlane(__float_as_int(ms[rr]), c));
      float xc = __int_as_float(__builtin_amdgcn_readlane(__float_as_int(xr[rr]), c));
      accL[rr] = fmaf(mc, wlc, accL[rr]);
      accR[rr] = fmaf(xc, wrc, accR[rr]);
    }
  }
#pragma unroll
  for (int rr = 0; rr < 4; ++rr)
    __builtin_nontemporal_store(accL[rr] + accR[rr] + bias,
                                &out[((size_t)(n0 + (w << 2) + rr) << 6) + lane]);
}

// ---------------------------------------------------------------------------
extern "C" void kernel_launch(void* const* d_in, const int* in_sizes, int n_in,
                              void* d_out, int out_size, void* d_ws, size_t ws_size,
                              hipStream_t stream) {
  const float* x  = (const float*)d_in[0];   // (8,64,32,32)
  const float* Wl = (const float*)d_in[1];   // (64,64)
  const float* bl = (const float*)d_in[2];   // (64,)
  const float* Wr = (const float*)d_in[3];   // (64,64)
  float* out = (float*)d_out;                // (8192,64)
  (void)d_ws; (void)ws_size;                 // workspace unused

  k_all<<<dim3(512), 256, 0, stream>>>(x, Wl, bl, Wr, out);
}